// Round 1
// 846.619 us; speedup vs baseline: 1.0511x; 1.0511x over previous
//
#include <hip/hip_runtime.h>
#include <math.h>

#define NEGV (-1e9f)
constexpr int B = 32, S = 4096, K = 512, H = 512;

typedef __attribute__((ext_vector_type(8))) short bf16x8;
typedef __attribute__((ext_vector_type(4))) float f32x4;
typedef __attribute__((ext_vector_type(4))) int i32x4;

__device__ __forceinline__ short f2bf(float x) {
  union { float f; unsigned u; } v; v.f = x;
  unsigned r = (v.u + 0x7FFFu + ((v.u >> 16) & 1u)) >> 16;
  return (short)r;
}

// packed f32x2 -> bf16x2 (RNE), 1 VALU instr for 2 elements (no builtin on gfx950)
__device__ __forceinline__ unsigned cvt_pk_bf16(float lo, float hi) {
  unsigned r;
  asm("v_cvt_pk_bf16_f32 %0, %1, %2" : "=v"(r) : "v"(lo), "v"(hi));
  return r;
}

__device__ __forceinline__ void cvt_store16(short* dst, const float4 a, const float4 b) {
  i32x4 t;
  t[0] = (int)cvt_pk_bf16(a.x, a.y);
  t[1] = (int)cvt_pk_bf16(a.z, a.w);
  t[2] = (int)cvt_pk_bf16(b.x, b.y);
  t[3] = (int)cvt_pk_bf16(b.z, b.w);
  *(i32x4*)dst = t;
}

__device__ __forceinline__ float fast_tanh(float x) {
  // tanh(x) = 1 - 2/(exp(2x)+1); accurate to ~1e-6, saturates correctly
  return 1.f - 2.f / (__expf(2.f * x) + 1.f);
}

// ---------------- K0: pre-swizzle Wk (f32) -> bf16 MFMA-B-fragment-major layout
// frag f = (c*32 + n)*64 + lane; lane holds B[k=c*32+(lane>>4)*8+j][h=n*16+(lane&15)]
__global__ __launch_bounds__(64)
void wkswizzle_kernel(const float* __restrict__ Wk_a, const float* __restrict__ Wk_b,
                      short* __restrict__ WkT) {
  const int head = blockIdx.y;
  const float* __restrict__ Wk = head ? Wk_b : Wk_a;
  const int cn = blockIdx.x;            // 0..511 : c*32+n
  const int c = cn >> 5, n = cn & 31;
  const int l = threadIdx.x;
  const int kb = c * 32 + ((l >> 4) << 3);
  const int h = n * 16 + (l & 15);
  bf16x8 frag;
#pragma unroll
  for (int j = 0; j < 8; ++j) frag[j] = f2bf(Wk[(size_t)(kb + j) * H + h]);
  *(bf16x8*)(WkT + (size_t)head * 262144 + ((size_t)cn * 64 + l) * 8) = frag;
}

// ---------------- K1: qproj[head][b][h] = query[b] @ Wq_head ----------------
__global__ __launch_bounds__(512)
void qproj_kernel(const float* __restrict__ query,
                  const float* __restrict__ Wq_a,
                  const float* __restrict__ Wq_b,
                  float* __restrict__ qproj) {
  const int b = blockIdx.x, head = blockIdx.y;
  const float* __restrict__ Wq = head ? Wq_b : Wq_a;
  __shared__ float qs[H];
  qs[threadIdx.x] = query[b * H + threadIdx.x];
  __syncthreads();
  const int h = threadIdx.x;
  float acc = 0.f;
#pragma unroll 8
  for (int k = 0; k < H; ++k) acc = fmaf(qs[k], Wq[k * H + h], acc);
  qproj[(head * B + b) * H + h] = acc;
}

// ---------------- K2: scores via bf16 MFMA, full-H block, BK=64, depth-2 prefetch.
// Block 512 (8 waves), tile 64s x 512h. Wave w owns h-tiles n = w*4 .. w*4+3.
// V staged once per tile through a 2x8KB LDS double buffer; f32->bf16 via v_cvt_pk_bf16_f32.
// A granule for chunk c+2 is global-loaded at iter c and LDS-written at end of iter c+1,
// so HBM latency (~900cy) is covered by ~2 chunk bodies. 8 barriers total.
// B frags stream from L2 (pre-swizzled WkT) straight into VGPRs — no LDS, no vmcnt@barrier.
__global__ __launch_bounds__(512, 2)
void scores_mfma_kernel(const float* __restrict__ values_a, const float* __restrict__ values_b,
                        const short* __restrict__ WkT,
                        const float* __restrict__ v_a, const float* __restrict__ v_b,
                        const float* __restrict__ qproj,
                        float* __restrict__ scores) {
  const int head = blockIdx.z, b = blockIdx.y;
  const int s0 = blockIdx.x * 64;
  const float* __restrict__ V  = (head ? values_b : values_a) + (size_t)b * S * K;
  const float* __restrict__ v  = head ? v_b : v_a;
  const float* __restrict__ qp = qproj + (head * B + b) * H;
  const short* __restrict__ wkb = WkT + (size_t)head * 262144;

  __shared__ __align__(16) short Albuf[2][4096];   // 2 x 8 KB : 64 rows x 64 k, frag-line major
  __shared__ float red[8 * 64];

  const int tid = threadIdx.x;
  const int w = tid >> 6, l = tid & 63;

  // A staging: thread t stages V[s0 + (t>>3)][c*64 + (t&7)*8 .. +7] (one b128 frag-line write)
  const int sa = tid >> 3, ka = (tid & 7) * 8;
  const float* const arow = V + (size_t)(s0 + sa) * K + ka;
  // frag line: k32-subchunk kk=ka>>5, row-tile i=sa>>4, lane=(sa&15)|(((ka&31)>>3)<<4), j=0..7
  const int aline = (((ka >> 5) * 4 + (sa >> 4)) * 64 + ((sa & 15) | (((ka & 31) >> 3) << 4))) * 8;
  // B frags: wave's h-tiles n = w*4 + nl
  const short* const bbase = wkb + ((w * 4) * 64 + l) * 8;

  f32x4 acc[4][4] = {};

  // prolog: load chunk0 + chunk1 into register slots, store chunk0 to LDS buf0
  float4 pfa[2], pfb[2];
  pfa[0] = *(const float4*)(arow);
  pfb[0] = *(const float4*)(arow + 4);
  pfa[1] = *(const float4*)(arow + 64);
  pfb[1] = *(const float4*)(arow + 68);
  cvt_store16(&Albuf[0][aline], pfa[0], pfb[0]);

#pragma unroll
  for (int c = 0; c < 8; ++c) {
    // B frag loads for this chunk (both k32 halves) — issued before the barrier
    bf16x8 bfr[2][4];
#pragma unroll
    for (int kk = 0; kk < 2; ++kk)
#pragma unroll
      for (int nl = 0; nl < 4; ++nl)
        bfr[kk][nl] = *(const bf16x8*)(bbase + ((2 * c + kk) * 32 + nl) * 512);
    // depth-2 A prefetch: chunk c+2 into the slot freed by chunk c
    if (c < 6) {
      pfa[c & 1] = *(const float4*)(arow + (c + 2) * 64);
      pfb[c & 1] = *(const float4*)(arow + (c + 2) * 64 + 4);
    }
    __syncthreads();   // lgkm-only: A writes of prev iter visible
#pragma unroll
    for (int kk = 0; kk < 2; ++kk) {
      bf16x8 afr[4];
#pragma unroll
      for (int i = 0; i < 4; ++i)
        afr[i] = *(const bf16x8*)(&Albuf[c & 1][((kk * 4 + i) * 64 + l) * 8]);
#pragma unroll
      for (int nl = 0; nl < 4; ++nl)
#pragma unroll
        for (int i = 0; i < 4; ++i)
          acc[i][nl] = __builtin_amdgcn_mfma_f32_16x16x32_bf16(afr[i], bfr[kk][nl], acc[i][nl], 0, 0, 0);
    }
    // convert + LDS-write chunk c+1 into the other buffer
    if (c < 7) cvt_store16(&Albuf[(c & 1) ^ 1][aline], pfa[(c + 1) & 1], pfb[(c + 1) & 1]);
  }

  // Epilogue: score[s] = sum_h v[h] * tanh(acc + qp[h]) ; h = (w*4+nl)*16 + (l&15)
  float qpr[4], vr[4];
#pragma unroll
  for (int nl = 0; nl < 4; ++nl) {
    const int h = (w * 4 + nl) * 16 + (l & 15);
    qpr[nl] = qp[h];
    vr[nl] = v[h];
  }
#pragma unroll
  for (int i = 0; i < 4; ++i)
#pragma unroll
    for (int r = 0; r < 4; ++r) {
      float p = 0.f;
#pragma unroll
      for (int nl = 0; nl < 4; ++nl) p = fmaf(vr[nl], fast_tanh(acc[i][nl][r] + qpr[nl]), p);
#pragma unroll
      for (int off = 8; off > 0; off >>= 1) p += __shfl_xor(p, off, 64);
      if ((l & 15) == 0) red[w * 64 + i * 16 + (l >> 4) * 4 + r] = p;
    }
  __syncthreads();
  if (tid < 64) {
    float tot = 0.f;
#pragma unroll
    for (int ww = 0; ww < 8; ++ww) tot += red[ww * 64 + tid];
    scores[((size_t)head * B + b) * S + s0 + tid] = tot;
  }
}

// ---------------- K3: sparsemax ----------------
__device__ __forceinline__ float bred256(float v, const bool is_max, float* lds) {
#pragma unroll
  for (int o = 32; o > 0; o >>= 1) {
    const float t = __shfl_xor(v, o, 64);
    v = is_max ? fmaxf(v, t) : (v + t);
  }
  __syncthreads();                       // protect lds from previous call's readers
  if ((threadIdx.x & 63) == 0) lds[threadIdx.x >> 6] = v;
  __syncthreads();
  return is_max ? fmaxf(fmaxf(lds[0], lds[1]), fmaxf(lds[2], lds[3]))
                : (lds[0] + lds[1]) + (lds[2] + lds[3]);
}

__global__ __launch_bounds__(256)
void sparsemax_kernel(const float* __restrict__ scores,
                      const int* __restrict__ mask_a, const int* __restrict__ mask_b,
                      float* __restrict__ d_out_f) {
  const int b = blockIdx.x, head = blockIdx.y;
  const float* __restrict__ z = scores + ((size_t)head * B + b) * S;
  const int* __restrict__ mask = (head ? mask_b : mask_a) + b * S;
  float* __restrict__ alpha = d_out_f + B * H + (size_t)head * B * S + (size_t)b * S;
  __shared__ float lds[4];
  const int tid = threadIdx.x;
  float e[16];
#pragma unroll
  for (int t = 0; t < 16; ++t) {
    const int s = t * 256 + tid;
    e[t] = mask[s] ? z[s] : NEGV;
  }
  float m = NEGV;
#pragma unroll
  for (int t = 0; t < 16; ++t) m = fmaxf(m, e[t]);
  m = bred256(m, true, lds);
  float lo = m - 1.f, hi = m;
  for (int it = 0; it < 28; ++it) {
    const float mid = 0.5f * (lo + hi);
    float s = 0.f;
#pragma unroll
    for (int t = 0; t < 16; ++t) s += fmaxf(e[t] - mid, 0.f);
    s = bred256(s, false, lds);
    if (s >= 1.f) lo = mid; else hi = mid;
  }
  float cnt = 0.f, sum = 0.f;
#pragma unroll
  for (int t = 0; t < 16; ++t) {
    if (e[t] > lo) { cnt += 1.f; sum += e[t]; }
  }
  cnt = bred256(cnt, false, lds);
  sum = bred256(sum, false, lds);
  const float tau = (sum - 1.f) / cnt;
#pragma unroll
  for (int t = 0; t < 16; ++t) alpha[t * 256 + tid] = fmaxf(e[t] - tau, 0.f);
}

// ---------------- K4: context = alphas @ values, exploiting sparsemax sparsity
__global__ __launch_bounds__(512)
void context_kernel(const float* __restrict__ values_a, const float* __restrict__ values_b,
                    const float* __restrict__ d_out_f, float* __restrict__ ctx) {
  const int b = blockIdx.x, head = blockIdx.y;
  const float* __restrict__ V = (head ? values_b : values_a) + (size_t)b * S * K;
  const float* __restrict__ al = d_out_f + B * H + (size_t)head * B * S + (size_t)b * S;
  __shared__ int cnt;
  __shared__ int sidx[S];
  __shared__ float sal[S];
  if (threadIdx.x == 0) cnt = 0;
  __syncthreads();
  for (int i = threadIdx.x; i < S; i += 512) {
    const float a = al[i];
    if (a > 0.f) { const int p = atomicAdd(&cnt, 1); sidx[p] = i; sal[p] = a; }
  }
  __syncthreads();
  const int n = cnt;
  const int j = threadIdx.x;
  float acc = 0.f;
  for (int t = 0; t < n; ++t) acc = fmaf(sal[t], V[(size_t)sidx[t] * K + j], acc);
  ctx[(head * B + b) * K + j] = acc;
}

// ---------------- K5: gate + candidates + output merge, one block per batch
__global__ __launch_bounds__(512)
void merge_kernel(const float* __restrict__ query, const float* __restrict__ ctx,
                  const float* __restrict__ Wg, const float* __restrict__ bg,
                  const float* __restrict__ Wu_a, const float* __restrict__ bu_a,
                  const float* __restrict__ Wu_b, const float* __restrict__ bu_b,
                  float* __restrict__ att) {
  const int b = blockIdx.x;
  __shared__ float gin[1536];
  __shared__ float lred[16];
  __shared__ float gw[2];
  const int tid = threadIdx.x;
  gin[tid]        = query[b * H + tid];
  gin[512 + tid]  = ctx[(0 * B + b) * K + tid];
  gin[1024 + tid] = ctx[(1 * B + b) * K + tid];
  __syncthreads();
  float p0 = 0.f, p1 = 0.f;
  for (int i = tid; i < 1536; i += 512) {
    const float x = gin[i];
    p0 = fmaf(x, Wg[i * 2 + 0], p0);
    p1 = fmaf(x, Wg[i * 2 + 1], p1);
  }
#pragma unroll
  for (int o = 32; o > 0; o >>= 1) { p0 += __shfl_xor(p0, o, 64); p1 += __shfl_xor(p1, o, 64); }
  if ((tid & 63) == 0) { lred[tid >> 6] = p0; lred[8 + (tid >> 6)] = p1; }
  __syncthreads();
  if (tid == 0) {
    float l0 = bg[0], l1 = bg[1];
    for (int w = 0; w < 8; ++w) { l0 += lred[w]; l1 += lred[8 + w]; }
    const float mx = fmaxf(l0, l1);
    const float e0 = expf(l0 - mx), e1 = expf(l1 - mx);
    gw[0] = e0 / (e0 + e1);
    gw[1] = e1 / (e0 + e1);
  }
  __syncthreads();
  const int h = tid;
  float aa = bu_a[h], ab = bu_b[h];
  for (int i = 0; i < 1024; ++i) aa = fmaf(gin[i], Wu_a[i * H + h], aa);
  for (int i = 0; i < 1024; ++i) {
    const float x = (i < 512) ? gin[i] : gin[i + 512];
    ab = fmaf(x, Wu_b[i * H + h], ab);
  }
  att[b * H + h] = gw[0] * tanhf(aa) + gw[1] * tanhf(ab);
}

extern "C" void kernel_launch(void* const* d_in, const int* in_sizes, int n_in,
                              void* d_out, int out_size, void* d_ws, size_t ws_size,
                              hipStream_t stream) {
  const float* query    = (const float*)d_in[0];
  const float* values_a = (const float*)d_in[1];
  const float* values_b = (const float*)d_in[2];
  const int*   mask_a   = (const int*)d_in[3];
  const int*   mask_b   = (const int*)d_in[4];
  const float* Wk_a = (const float*)d_in[5];
  const float* Wq_a = (const float*)d_in[6];
  const float* v_a  = (const float*)d_in[7];
  const float* Wk_b = (const float*)d_in[8];
  const float* Wq_b = (const float*)d_in[9];
  const float* v_b  = (const float*)d_in[10];
  const float* Wg   = (const float*)d_in[11];
  const float* bg   = (const float*)d_in[12];
  const float* Wu_a = (const float*)d_in[13];
  const float* bu_a = (const float*)d_in[14];
  const float* Wu_b = (const float*)d_in[15];
  const float* bu_b = (const float*)d_in[16];
  float* out = (float*)d_out;

  float* wsf    = (float*)d_ws;
  float* qproj  = wsf;                                   // [2][B][H]    32K f
  float* scores = wsf + 2 * B * H;                       // [2][B][S]   256K f
  float* ctx    = wsf + 2 * B * H + 2 * B * S;           // [2][B][K]    32K f
  short* WkT    = (short*)(wsf + 2 * B * H + 2 * B * S + 2 * B * K);  // 2 x 262144 bf16

  wkswizzle_kernel<<<dim3(512, 2), 64, 0, stream>>>(Wk_a, Wk_b, WkT);
  qproj_kernel<<<dim3(B, 2), 512, 0, stream>>>(query, Wq_a, Wq_b, qproj);
  scores_mfma_kernel<<<dim3(S / 64, B, 2), 512, 0, stream>>>(
      values_a, values_b, WkT, v_a, v_b, qproj, scores);
  sparsemax_kernel<<<dim3(B, 2), 256, 0, stream>>>(scores, mask_a, mask_b, out);
  context_kernel<<<dim3(B, 2), 512, 0, stream>>>(values_a, values_b, out, ctx);
  merge_kernel<<<B, 512, 0, stream>>>(query, ctx, Wg, bg, Wu_a, bu_a, Wu_b, bu_b, out);
}